// Round 5
// baseline (1976.049 us; speedup 1.0000x reference)
//
#include <hip/hip_runtime.h>

typedef short s16x8 __attribute__((ext_vector_type(8)));
typedef float f32x4 __attribute__((ext_vector_type(4)));

// ---------- helpers ----------
__device__ __forceinline__ unsigned short f2bf(float f) {
    unsigned int u = __builtin_bit_cast(unsigned int, f);
    u += 0x7fffu + ((u >> 16) & 1u);           // round-to-nearest-even
    return (unsigned short)(u >> 16);
}

__device__ __forceinline__ void gload16(const void* g, void* l) {
    __builtin_amdgcn_global_load_lds(
        (const __attribute__((address_space(1))) unsigned int*)g,
        (__attribute__((address_space(3))) unsigned int*)l,
        16, 0, 0);
}

// ---------- phase 1: fp32 -> bf16 casts ----------
__global__ void cast_bf16_kernel(const float* __restrict__ src,
                                 unsigned short* __restrict__ dst, int n4) {
    int i = blockIdx.x * 256 + threadIdx.x;
    if (i >= n4) return;
    float4 v = ((const float4*)src)[i];
    ushort4 o;
    o.x = f2bf(v.x); o.y = f2bf(v.y); o.z = f2bf(v.z); o.w = f2bf(v.w);
    ((ushort4*)dst)[i] = o;
}

// ---------- phase 2: gather relative position bias rpb[h][64][64] ----------
__global__ void rpb_kernel(const float* __restrict__ table,
                           const int* __restrict__ rel,
                           float* __restrict__ rpb) {
    int t = blockIdx.x * 64 + threadIdx.x;     // 0..4095  (i*64+j)
    int idx = rel[t];
#pragma unroll
    for (int h = 0; h < 16; ++h)
        rpb[h * 4096 + t] = table[idx * 16 + h];
}

// ---------- K-loop building blocks (BM=128, BN=256, BK=32) ----------
// LDS per buffer: A 128x32 (4096 shorts) + B 256x32 (8192 shorts) = 12288.
// Granule swizzle: LDS slot s at row r holds global granule s ^ ((r>>1)&3);
// source-permuted (dest linear, required by global_load_lds), read XORs key.
__device__ __forceinline__ void stage_step(const unsigned short* __restrict__ Ab,
                                           const unsigned short* __restrict__ Bb,
                                           unsigned short* base, int wave,
                                           size_t g0, size_t g1, size_t g2,
                                           size_t g3, int k0) {
    gload16(Ab + g0 + k0, &base[wave * 512]);
    gload16(Ab + g1 + k0, &base[2048 + wave * 512]);
    gload16(Bb + g0 + k0, &base[4096 + wave * 512]);
    gload16(Bb + g1 + k0, &base[6144 + wave * 512]);
    gload16(Bb + g2 + k0, &base[8192 + wave * 512]);
    gload16(Bb + g3 + k0, &base[10240 + wave * 512]);
}

// SW=true : acc[j*4+i] = mfma(bf[j], af[i]) -> reg quad = 4 consecutive B-rows
// SW=false: acc[i*8+j] = mfma(af[i], bf[j]) -> reg quad = 4 consecutive A-rows
template <bool SW>
__device__ __forceinline__ void mfma_step(const unsigned short* base, int ln, int hk,
                                          int wr, int wc, f32x4 (&acc)[32]) {
    const unsigned short* Al = base;
    const unsigned short* Bl = base + 4096;
    const int sl = hk ^ ((ln >> 1) & 3);       // swizzled granule slot
    s16x8 af[4], bf[8];
#pragma unroll
    for (int i = 0; i < 4; ++i)
        af[i] = *(const s16x8*)&Al[(wr + i * 16 + ln) * 32 + sl * 8];
#pragma unroll
    for (int j = 0; j < 8; ++j)
        bf[j] = *(const s16x8*)&Bl[(wc + j * 16 + ln) * 32 + sl * 8];
#pragma unroll
    for (int i = 0; i < 4; ++i)
#pragma unroll
        for (int j = 0; j < 8; ++j) {
            if constexpr (SW)
                acc[j * 4 + i] = __builtin_amdgcn_mfma_f32_16x16x32_bf16(bf[j], af[i], acc[j * 4 + i], 0, 0, 0);
            else
                acc[i * 8 + j] = __builtin_amdgcn_mfma_f32_16x16x32_bf16(af[i], bf[j], acc[i * 8 + j], 0, 0, 0);
        }
}

// Double-buffered K-loop (K=512): stage tile t+1 while computing tile t.
template <bool SW>
__device__ __forceinline__ void kloop(const unsigned short* __restrict__ Ab,
                                      const unsigned short* __restrict__ Bb,
                                      unsigned short* smem,
                                      int t, int wave, int ln, int hk,
                                      int wr, int wc, f32x4 (&acc)[32]) {
    const int row = t >> 2;
    const int cgs = (t & 3) ^ ((t >> 3) & 3);  // source granule permute
    const size_t g0 = (size_t)row * 512 + cgs * 8;
    const size_t g1 = (size_t)(row + 64) * 512 + cgs * 8;
    const size_t g2 = (size_t)(row + 128) * 512 + cgs * 8;
    const size_t g3 = (size_t)(row + 192) * 512 + cgs * 8;
    unsigned short* b0 = smem;
    unsigned short* b1 = smem + 12288;

    stage_step(Ab, Bb, b0, wave, g0, g1, g2, g3, 0);
    __syncthreads();
    for (int k0 = 0; k0 < 512; k0 += 64) {
        stage_step(Ab, Bb, b1, wave, g0, g1, g2, g3, k0 + 32);
        mfma_step<SW>(b0, ln, hk, wr, wc, acc);
        __syncthreads();
        if (k0 + 64 < 512)
            stage_step(Ab, Bb, b0, wave, g0, g1, g2, g3, k0 + 64);
        mfma_step<SW>(b1, ln, hk, wr, wc, acc);
        __syncthreads();
    }
}

// ---------- GEMM C = A(MxK) * B(NxK)^T, bf16 in, fp32 acc ----------
// 128x256 tile, 4 waves in 2x2 (each 64 rows x 128 cols).
// MODE 0: qkv proj -> q/k (swapped, scale folded into q) and v^T (normal),
//         barrier-free per-wave LDS repack -> coalesced 16B stores.
// MODE 1: out proj (swapped) -> float4 fp32 stores.
template <int MODE, int NCOLS>
__global__ __launch_bounds__(256, 3) void gemm_bt(
    const unsigned short* __restrict__ A, const unsigned short* __restrict__ B,
    const float* __restrict__ bq, const float* __restrict__ bv,
    unsigned short* __restrict__ qb, unsigned short* __restrict__ kb,
    unsigned short* __restrict__ vtb,
    const float* __restrict__ pb, float* __restrict__ out) {
    // 48KB: 2 x 12288-short staging buffers; epilogue reuses as 4 x 2560-short
    // wave-private repack regions (post final barrier, wave-private -> safe).
    __shared__ __align__(16) unsigned short smem[24576];

    constexpr int NBN = NCOLS / 256;
    // XCD-chunked swizzle (grid % 8 == 0)
    const unsigned int cpx = gridDim.x >> 3;
    const unsigned int wg = (blockIdx.x & 7u) * cpx + (blockIdx.x >> 3);
    const int bm = wg / NBN;
    const int bn = wg % NBN;
    const int t = threadIdx.x;
    const int wave = t >> 6, lane = t & 63;
    const int ln = lane & 15, hk = lane >> 4;
    const int wr = (wave >> 1) * 64, wc = (wave & 1) * 128;

    const f32x4 zero = {0.f, 0.f, 0.f, 0.f};
    f32x4 acc[32];
#pragma unroll
    for (int i = 0; i < 32; ++i) acc[i] = zero;

    const unsigned short* Ab = A + (size_t)bm * 128 * 512;
    const unsigned short* Bb = B + (size_t)bn * 256 * 512;

    if constexpr (MODE == 1) {
        kloop<true>(Ab, Bb, smem, t, wave, ln, hk, wr, wc, acc);
        // per-wave fp32 region [64 tok][20 words]
        float* epf = (float*)smem + wave * 1280;
#pragma unroll
        for (int j = 0; j < 8; ++j) {
            const int nn0 = bn * 256 + wc + j * 16 + hk * 4;
            const float4 b4 = *(const float4*)&pb[nn0];
#pragma unroll
            for (int i = 0; i < 4; ++i) {
                const int tk = i * 16 + ln;
                float4 o4;
                o4.x = acc[j * 4 + i][0] + b4.x;
                o4.y = acc[j * 4 + i][1] + b4.y;
                o4.z = acc[j * 4 + i][2] + b4.z;
                o4.w = acc[j * 4 + i][3] + b4.w;
                *(float4*)&epf[tk * 20 + hk * 4] = o4;
            }
            const int nnb = bn * 256 + wc + j * 16;
#pragma unroll
            for (int rr = 0; rr < 4; ++rr) {
                const int li = rr * 64 + lane;
                const int tk = li >> 2, c4 = (li & 3) * 4;
                float4 v4 = *(const float4*)&epf[tk * 20 + c4];
                *(float4*)(out + (size_t)(bm * 128 + wr + tk) * NCOLS + nnb + c4) = v4;
            }
        }
    } else {
        const int which = bn >> 1;             // 0=q, 1=k, 2=v  (NBN=6)
        const int bb = bm * 2;                 // tile spans windows bb, bb+1
        const size_t winbase = (size_t)((bb + (wr >> 6)) * 16);
        unsigned short* ep = smem + wave * 2560;
        if (which < 2) {
            // swapped: regs = 4 consecutive d-channels at one token
            kloop<true>(Ab, Bb, smem, t, wave, ln, hk, wr, wc, acc);
            unsigned short* dst0 = (which == 0) ? qb : kb;
            const float qsc = (which == 0) ? 0.17677669529663687f : 1.f;
#pragma unroll
            for (int Q = 0; Q < 4; ++Q) {      // quarter = 32 channels = 1 head
#pragma unroll
                for (int j2 = 0; j2 < 2; ++j2) {
                    const int j = Q * 2 + j2;
                    const int rem0 = (bn & 1) * 256 + wc + j * 16 + hk * 4;
                    float4 b4 = {0.f, 0.f, 0.f, 0.f};
                    if (which == 0) b4 = *(const float4*)&bq[rem0];
                    const int ch0 = j2 * 16 + hk * 4;
#pragma unroll
                    for (int i = 0; i < 4; ++i) {
                        const int tk = i * 16 + ln;
                        ushort4 pk;
                        pk.x = f2bf((acc[j * 4 + i][0] + b4.x) * qsc);
                        pk.y = f2bf((acc[j * 4 + i][1] + b4.y) * qsc);
                        pk.z = f2bf((acc[j * 4 + i][2] + b4.z) * qsc);
                        pk.w = f2bf((acc[j * 4 + i][3] + b4.w) * qsc);
                        *(ushort4*)&ep[tk * 40 + ch0] = pk;
                    }
                }
                const int remQ = (bn & 1) * 256 + wc + Q * 32;
                const size_t Dq = (winbase + (remQ >> 5)) * 2048;
#pragma unroll
                for (int rr = 0; rr < 4; ++rr) {      // 1KB contiguous / wave-instr
                    const int li = rr * 64 + lane;
                    const int tk = li >> 2, c8 = (li & 3) * 8;
                    s16x8 val = *(const s16x8*)&ep[tk * 40 + c8];
                    *(s16x8*)(dst0 + Dq + tk * 32 + c8) = val;
                }
            }
        } else {
            // normal: regs = 4 consecutive tokens at one d-channel -> v^T
            kloop<false>(Ab, Bb, smem, t, wave, ln, hk, wr, wc, acc);
#pragma unroll
            for (int Q = 0; Q < 4; ++Q) {      // quarter = 32 channels = 1 head
#pragma unroll
                for (int j2 = 0; j2 < 2; ++j2) {
                    const int j = Q * 2 + j2;
                    const int rem = (bn & 1) * 256 + wc + j * 16 + ln;
                    const float bias = bv[rem];
                    const int ch = j2 * 16 + ln;
#pragma unroll
                    for (int i = 0; i < 4; ++i) {
                        const int tk = i * 16 + hk * 4;
                        ushort4 pk;
                        pk.x = f2bf(acc[i * 8 + j][0] + bias);
                        pk.y = f2bf(acc[i * 8 + j][1] + bias);
                        pk.z = f2bf(acc[i * 8 + j][2] + bias);
                        pk.w = f2bf(acc[i * 8 + j][3] + bias);
                        *(ushort4*)&ep[ch * 72 + tk] = pk;
                    }
                }
                const int remQ = (bn & 1) * 256 + wc + Q * 32;
                const size_t Dv = (winbase + (remQ >> 5)) * 2048;
#pragma unroll
                for (int rr = 0; rr < 4; ++rr) {      // 1KB contiguous / wave-instr
                    const int li = rr * 64 + lane;
                    const int dd = li >> 3, t8 = (li & 7) * 8;
                    s16x8 val = *(const s16x8*)&ep[dd * 72 + t8];
                    *(s16x8*)(vtb + Dv + dd * 64 + t8) = val;
                }
            }
        }
    }
}

// ---------- phase 4: attention, one block per (b, head) ----------
// Swapped QK^T: sc[j] = mfma(K, Q) -> lane (ln,hk) holds S[k=j*16+hk*4+r][q],
// q = wave*16+ln.  Row-softmax needs only shfl_xor(16/32); rpb/mask loads are
// float4 (k-contiguous per lane).  Scale pre-folded into q at QKV epilogue.
__global__ __launch_bounds__(256) void attn_kernel(
    const unsigned short* __restrict__ qbuf, const unsigned short* __restrict__ kbuf,
    const unsigned short* __restrict__ vtbuf, const float* __restrict__ rpb,
    const float* __restrict__ mask, unsigned short* __restrict__ aout) {
    __shared__ __align__(16) unsigned short ql[64 * 32];   // Q [tok][4 gr][8]
    __shared__ __align__(16) unsigned short kl[64 * 32];   // K [tok][4 gr][8]
    __shared__ __align__(16) unsigned short vl[32 * 64];   // V^T [d][8 gr][8]
    __shared__ __align__(16) unsigned short plds[64 * 72]; // P bf16, padded stride

    const int bh = blockIdx.x;
    const int b = bh >> 4, head = bh & 15;
    const int wmask = b & 255;               // window index = b % NW
    const int t = threadIdx.x, wave = t >> 6, lane = t & 63;
    const int ln = lane & 15, hk = lane >> 4;

    const size_t base = (size_t)bh * 2048;
    // source-permuted staging (dest linear): q/k key=(row>>1)&3, v key=row&7
    {
        const int r4 = t >> 2, c4 = t & 3;
        const int qs = c4 ^ ((t >> 3) & 3);
        gload16(qbuf + base + r4 * 32 + qs * 8, &ql[wave * 512]);
        gload16(kbuf + base + r4 * 32 + qs * 8, &kl[wave * 512]);
        const int r8 = t >> 3, c8v = t & 7;
        const int vs = c8v ^ (r8 & 7);
        gload16(vtbuf + base + r8 * 64 + vs * 8, &vl[wave * 512]);
    }
    __syncthreads();

    const f32x4 zero = {0.f, 0.f, 0.f, 0.f};
    const int slq = hk ^ ((ln >> 1) & 3);     // q/k swizzled slot
    s16x8 aq = *(const s16x8*)&ql[(wave * 16 + ln) * 32 + slq * 8];
    f32x4 sc[4];
#pragma unroll
    for (int j = 0; j < 4; ++j) {
        s16x8 bk = *(const s16x8*)&kl[(j * 16 + ln) * 32 + slq * 8];
        sc[j] = __builtin_amdgcn_mfma_f32_16x16x32_bf16(bk, aq, zero, 0, 0, 0);
    }

    const int q = wave * 16 + ln;            // this lane's q-row
    const float4* rp4 = (const float4*)(rpb + head * 4096);
    const float4* mk4 = (const float4*)(mask + wmask * 4096);

    float p[4][4];
    float m = -1e30f;
#pragma unroll
    for (int j = 0; j < 4; ++j) {
        const float4 rb = rp4[q * 16 + j * 4 + hk];
        const float4 mk = mk4[q * 16 + j * 4 + hk];
        p[j][0] = sc[j][0] + rb.x + mk.x;
        p[j][1] = sc[j][1] + rb.y + mk.y;
        p[j][2] = sc[j][2] + rb.z + mk.z;
        p[j][3] = sc[j][3] + rb.w + mk.w;
#pragma unroll
        for (int r = 0; r < 4; ++r) m = fmaxf(m, p[j][r]);
    }
    m = fmaxf(m, __shfl_xor(m, 16));
    m = fmaxf(m, __shfl_xor(m, 32));
    float s = 0.f;
#pragma unroll
    for (int j = 0; j < 4; ++j)
#pragma unroll
        for (int r = 0; r < 4; ++r) { p[j][r] = __expf(p[j][r] - m); s += p[j][r]; }
    s += __shfl_xor(s, 16);
    s += __shfl_xor(s, 32);
    const float inv = 1.f / s;

    // P write: lane owns row q, k = j*16+hk*4+r -> packed ds_write_b64
    // (rows wave-private: written q=wave*16+ln, read q=wave*16+ln -> no barrier)
#pragma unroll
    for (int j = 0; j < 4; ++j) {
        ushort4 pk;
        pk.x = f2bf(p[j][0] * inv);
        pk.y = f2bf(p[j][1] * inv);
        pk.z = f2bf(p[j][2] * inv);
        pk.w = f2bf(p[j][3] * inv);
        *(ushort4*)&plds[q * 72 + j * 16 + hk * 4] = pk;
    }

    // O^T = (P V)^T via swapped operands: regs = 4 consecutive d at one token
    f32x4 o2[2] = {zero, zero};
#pragma unroll
    for (int kt = 0; kt < 2; ++kt) {
        s16x8 ap = *(const s16x8*)&plds[(wave * 16 + ln) * 72 + kt * 32 + hk * 8];
#pragma unroll
        for (int nt = 0; nt < 2; ++nt) {
            const int vsl = (kt * 4 + hk) ^ (ln & 7);   // v swizzled slot
            s16x8 bvf = *(const s16x8*)&vl[(nt * 16 + ln) * 64 + vsl * 8];
            o2[nt] = __builtin_amdgcn_mfma_f32_16x16x32_bf16(bvf, ap, o2[nt], 0, 0, 0);
        }
    }
    // coalesce aout stores through a wave-private slice of plds
    unsigned short* ep = plds + wave * 1152;   // rows wave*16.. (own rows)
#pragma unroll
    for (int nt = 0; nt < 2; ++nt) {
        ushort4 pk;
        pk.x = f2bf(o2[nt][0]); pk.y = f2bf(o2[nt][1]);
        pk.z = f2bf(o2[nt][2]); pk.w = f2bf(o2[nt][3]);
        *(ushort4*)&ep[ln * 40 + nt * 16 + hk * 4] = pk;
    }
    const int tk = lane >> 2, c8 = (lane & 3) * 8;
    s16x8 val = *(const s16x8*)&ep[tk * 40 + c8];
    *(s16x8*)(aout + ((size_t)(b * 64 + wave * 16 + tk)) * 512 + head * 32 + c8) = val;
}

// ---------- launcher ----------
extern "C" void kernel_launch(void* const* d_in, const int* in_sizes, int n_in,
                              void* d_out, int out_size, void* d_ws, size_t ws_size,
                              hipStream_t stream) {
    const float* x      = (const float*)d_in[0];
    const float* mask   = (const float*)d_in[1];
    const float* qkv_w  = (const float*)d_in[2];
    const float* q_bias = (const float*)d_in[3];
    const float* v_bias = (const float*)d_in[4];
    const float* rpb_t  = (const float*)d_in[5];
    const float* proj_w = (const float*)d_in[6];
    const float* proj_b = (const float*)d_in[7];
    const int*   rel    = (const int*)d_in[8];
    float* out = (float*)d_out;

    char* ws = (char*)d_ws;
    unsigned short* xbf   = (unsigned short*)ws;                  // 128 MiB, reused as attn_out
    unsigned short* qbuf  = (unsigned short*)(ws + 0x08000000);   // 128 MiB
    unsigned short* kbuf  = (unsigned short*)(ws + 0x10000000);   // 128 MiB
    unsigned short* vtbuf = (unsigned short*)(ws + 0x18000000);   // 128 MiB
    unsigned short* wqkv  = (unsigned short*)(ws + 0x20000000);   // 1.5 MiB
    unsigned short* wproj = (unsigned short*)(ws + 0x20180000);   // 0.5 MiB
    float*          rpb   = (float*)(ws + 0x20200000);            // 0.25 MiB
    unsigned short* aout  = xbf;

    cast_bf16_kernel<<<65536, 256, 0, stream>>>(x, xbf, 16777216);
    cast_bf16_kernel<<<768, 256, 0, stream>>>(qkv_w, wqkv, 196608);
    cast_bf16_kernel<<<256, 256, 0, stream>>>(proj_w, wproj, 65536);
    rpb_kernel<<<64, 64, 0, stream>>>(rpb_t, rel, rpb);

    gemm_bt<0, 1536><<<6144, 256, 0, stream>>>(
        xbf, wqkv, q_bias, v_bias, qbuf, kbuf, vtbuf, nullptr, nullptr);

    attn_kernel<<<32768, 256, 0, stream>>>(qbuf, kbuf, vtbuf, rpb, mask, aout);

    gemm_bt<1, 512><<<2048, 256, 0, stream>>>(
        aout, wproj, nullptr, nullptr, nullptr, nullptr, nullptr, proj_b, out);
}